// Round 1
// baseline (1332.457 us; speedup 1.0000x reference)
//
#include <hip/hip_runtime.h>
#include <stdint.h>

// Problem constants (fixed instance, per reference setup_inputs()):
#define N_NODES 102400
#define N_EDGES 409600
#define N_GRAPHS 2048
#define F_IN 78      // x features; W1: 78->78
#define F_H1 78
#define F_H2 156     // W2: 78->156
#define F_H3 312     // W3: 156->312
#define F_OUT 200    // Wfc: 312->200

// ---------------- degree / CSR build ----------------

__global__ void deg_kernel(const int* __restrict__ dst, int E, int* __restrict__ deg) {
    int e = blockIdx.x * blockDim.x + threadIdx.x;
    if (e < E) atomicAdd(&deg[dst[e]], 1);
}

__global__ void dinv_kernel(const int* __restrict__ deg, float* __restrict__ dinv, int n) {
    int i = blockIdx.x * blockDim.x + threadIdx.x;
    if (i < n) dinv[i] = rsqrtf((float)deg[i] + 1.0f);
}

// Single-workgroup exclusive scan of deg -> offs (and cursor copy). n = 102400.
__global__ void scan_kernel(const int* __restrict__ deg, int* __restrict__ offs,
                            int* __restrict__ cursor, int n) {
    __shared__ int sh[1024];
    __shared__ int carry_sh;
    int tid = threadIdx.x;
    if (tid == 0) carry_sh = 0;
    __syncthreads();
    for (int base = 0; base < n; base += 1024) {
        int i = base + tid;
        int v = (i < n) ? deg[i] : 0;
        sh[tid] = v;
        __syncthreads();
        for (int off = 1; off < 1024; off <<= 1) {
            int t = (tid >= off) ? sh[tid - off] : 0;
            __syncthreads();
            sh[tid] += t;
            __syncthreads();
        }
        int incl = sh[tid];
        int carry = carry_sh;
        if (i < n) {
            int excl = carry + incl - v;
            offs[i] = excl;
            cursor[i] = excl;
        }
        __syncthreads();
        if (tid == 1023) carry_sh = carry + sh[1023];
        __syncthreads();
    }
    if (tid == 0) offs[n] = carry_sh;
}

__global__ void fill_kernel(const int* __restrict__ src, const int* __restrict__ dst, int E,
                            int* __restrict__ cursor, int* __restrict__ csr_src,
                            float* __restrict__ csr_w, const float* __restrict__ dinv) {
    int e = blockIdx.x * blockDim.x + threadIdx.x;
    if (e >= E) return;
    int s = src[e], d = dst[e];
    int pos = atomicAdd(&cursor[d], 1);
    csr_src[pos] = s;
    csr_w[pos] = dinv[s] * dinv[d];
}

// ---------------- to_dense_batch row mapping ----------------

__global__ void start_kernel(const int* __restrict__ batch, int n, int* __restrict__ startb) {
    int i = blockIdx.x * blockDim.x + threadIdx.x;
    if (i >= n) return;
    if (i == 0 || batch[i] != batch[i - 1]) startb[batch[i]] = i;
}

__global__ void rowmap_kernel(const int* __restrict__ batch, const int* __restrict__ startb,
                              const int* __restrict__ pmax, int n, int* __restrict__ rowmap) {
    int i = blockIdx.x * blockDim.x + threadIdx.x;
    if (i >= n) return;
    int b = batch[i];
    int mx = *pmax;
    int pos = i - startb[b];
    rowmap[i] = (pos < mx) ? (b * mx + pos) : -1;
}

// ---------------- aggregation: out[n,:] = dinv[n]^2*H[n,:] + sum_in w*H[src,:] ----------------

__global__ void agg_kernel(const float* __restrict__ H, int F,
                           const int* __restrict__ offs, const int* __restrict__ csr_src,
                           const float* __restrict__ csr_w, const float* __restrict__ dinv,
                           float* __restrict__ out, int n) {
    int gw = (blockIdx.x * blockDim.x + threadIdx.x) >> 6;  // one wave per node
    int lane = threadIdx.x & 63;
    if (gw >= n) return;
    float di = dinv[gw];
    float sw = di * di;
    int e0 = offs[gw], e1 = offs[gw + 1];
    for (int f0 = 0; f0 < F; f0 += 64) {
        int f = f0 + lane;
        bool ok = (f < F);
        float acc = ok ? sw * H[gw * F + f] : 0.0f;
        for (int j = e0; j < e1; ++j) {
            int s = csr_src[j];
            float w = csr_w[j];
            if (ok) acc += w * H[s * F + f];
        }
        if (ok) out[gw * F + f] = acc;
    }
}

// ---------------- fp32 tiled GEMM: C = A[nrows,K] @ W[K,Fout] + bias, opt relu, opt rowmap ----------------

__global__ __launch_bounds__(256) void gemm_kernel(
    const float* __restrict__ A, int K,
    const float* __restrict__ W, int Fout,
    const float* __restrict__ bias,
    float* __restrict__ C, int ldc,
    const int* __restrict__ rowmap, int relu, int nrows) {
    __shared__ float As[16][65];  // [kk][row]
    __shared__ float Ws[16][65];  // [kk][col]
    int tid = threadIdx.x;
    int tx = tid & 15;
    int ty = tid >> 4;
    int r0 = blockIdx.y * 64;
    int c0 = blockIdx.x * 64;
    float acc[4][4] = {};
    for (int k0 = 0; k0 < K; k0 += 16) {
#pragma unroll
        for (int i = 0; i < 4; ++i) {  // A tile: 64 rows x 16 k
            int idx = tid + i * 256;
            int kk = idx & 15, r = idx >> 4;
            int kg = k0 + kk;
            As[kk][r] = (kg < K) ? A[(r0 + r) * K + kg] : 0.0f;
        }
#pragma unroll
        for (int i = 0; i < 4; ++i) {  // W tile: 16 k x 64 cols
            int idx = tid + i * 256;
            int c = idx & 63, kk = idx >> 6;
            int kg = k0 + kk, cg = c0 + c;
            Ws[kk][c] = (kg < K && cg < Fout) ? W[kg * Fout + cg] : 0.0f;
        }
        __syncthreads();
#pragma unroll
        for (int kk = 0; kk < 16; ++kk) {
            float a[4], w[4];
#pragma unroll
            for (int i = 0; i < 4; ++i) a[i] = As[kk][ty + i * 16];
#pragma unroll
            for (int j = 0; j < 4; ++j) w[j] = Ws[kk][tx + j * 16];
#pragma unroll
            for (int i = 0; i < 4; ++i)
#pragma unroll
                for (int j = 0; j < 4; ++j) acc[i][j] += a[i] * w[j];
        }
        __syncthreads();
    }
#pragma unroll
    for (int i = 0; i < 4; ++i) {
        int row = r0 + ty + i * 16;
        int drow = rowmap ? rowmap[row] : row;
        if (drow < 0) continue;
#pragma unroll
        for (int j = 0; j < 4; ++j) {
            int col = c0 + tx + j * 16;
            if (col < Fout) {
                float v = acc[i][j] + bias[col];
                if (relu) v = fmaxf(v, 0.0f);
                C[drow * ldc + col] = v;
            }
        }
    }
}

// ---------------- launch ----------------

static inline char* align256(char* p) {
    return (char*)(((uintptr_t)p + 255) & ~(uintptr_t)255);
}

extern "C" void kernel_launch(void* const* d_in, const int* in_sizes, int n_in,
                              void* d_out, int out_size, void* d_ws, size_t ws_size,
                              hipStream_t stream) {
    const int N = N_NODES, E = N_EDGES;
    const float* x = (const float*)d_in[0];
    const int* ei = (const int*)d_in[1];
    const int* src = ei;
    const int* dst = ei + E;
    const int* batch = (const int*)d_in[2];
    const int* pmax = (const int*)d_in[3];
    const float* W1 = (const float*)d_in[4];
    const float* b1 = (const float*)d_in[5];
    const float* W2 = (const float*)d_in[6];
    const float* b2 = (const float*)d_in[7];
    const float* W3 = (const float*)d_in[8];
    const float* b3 = (const float*)d_in[9];
    const float* Wfc = (const float*)d_in[10];
    const float* bfc = (const float*)d_in[11];
    float* out = (float*)d_out;

    // workspace carve (~197 MB)
    char* p = (char*)d_ws;
    float* dinv = (float*)p;     p = align256(p + (size_t)N * 4);
    int* deg = (int*)p;          p = align256(p + (size_t)N * 4);
    int* offs = (int*)p;         p = align256(p + (size_t)(N + 1) * 4);
    int* cursor = (int*)p;       p = align256(p + (size_t)N * 4);
    int* csr_src = (int*)p;      p = align256(p + (size_t)E * 4);
    float* csr_w = (float*)p;    p = align256(p + (size_t)E * 4);
    int* startb = (int*)p;       p = align256(p + (size_t)N_GRAPHS * 4);
    int* rowmap = (int*)p;       p = align256(p + (size_t)N * 4);
    float* bufA = (float*)p;     p = align256(p + (size_t)N * F_H2 * 4);  // max 156 wide
    float* bufB = (float*)p;     p = align256(p + (size_t)N * F_H3 * 4);  // max 312 wide

    // degree + CSR
    hipMemsetAsync(deg, 0, (size_t)N * 4, stream);
    deg_kernel<<<(E + 255) / 256, 256, 0, stream>>>(dst, E, deg);
    dinv_kernel<<<(N + 255) / 256, 256, 0, stream>>>(deg, dinv, N);
    scan_kernel<<<1, 1024, 0, stream>>>(deg, offs, cursor, N);
    fill_kernel<<<(E + 255) / 256, 256, 0, stream>>>(src, dst, E, cursor, csr_src, csr_w, dinv);

    // dense-batch row mapping
    start_kernel<<<(N + 255) / 256, 256, 0, stream>>>(batch, N, startb);
    rowmap_kernel<<<(N + 255) / 256, 256, 0, stream>>>(batch, startb, pmax, N, rowmap);

    // Layer 1: agg(x) [N,78] -> @W1 + b1, relu -> bufB [N,78]
    agg_kernel<<<N / 4, 256, 0, stream>>>(x, F_IN, offs, csr_src, csr_w, dinv, bufA, N);
    gemm_kernel<<<dim3((F_H1 + 63) / 64, N / 64), 256, 0, stream>>>(
        bufA, F_IN, W1, F_H1, b1, bufB, F_H1, nullptr, 1, N);

    // Layer 2: agg(h1) [N,78] -> @W2 + b2, relu -> bufB [N,156]
    agg_kernel<<<N / 4, 256, 0, stream>>>(bufB, F_H1, offs, csr_src, csr_w, dinv, bufA, N);
    gemm_kernel<<<dim3((F_H2 + 63) / 64, N / 64), 256, 0, stream>>>(
        bufA, F_H1, W2, F_H2, b2, bufB, F_H2, nullptr, 1, N);

    // Layer 3: agg(h2) [N,156] -> @W3 + b3, relu -> bufB [N,312]
    agg_kernel<<<N / 4, 256, 0, stream>>>(bufB, F_H2, offs, csr_src, csr_w, dinv, bufA, N);
    gemm_kernel<<<dim3((F_H3 + 63) / 64, N / 64), 256, 0, stream>>>(
        bufA, F_H2, W3, F_H3, b3, bufB, F_H3, nullptr, 1, N);

    // FC + fused to_dense_batch scatter
    hipMemsetAsync(out, 0, (size_t)out_size * sizeof(float), stream);
    gemm_kernel<<<dim3((F_OUT + 63) / 64, N / 64), 256, 0, stream>>>(
        bufB, F_H3, Wfc, F_OUT, bfc, out, F_OUT, rowmap, 0, N);
}

// Round 2
// 447.478 us; speedup vs baseline: 2.9777x; 2.9777x over previous
//
#include <hip/hip_runtime.h>
#include <hip/hip_bf16.h>
#include <stdint.h>

#define N_NODES 102400
#define N_EDGES 409600
#define N_GRAPHS 2048

typedef __attribute__((ext_vector_type(8))) short short8;
typedef __attribute__((ext_vector_type(4))) float f32x4;

// ---------------- degree / CSR build ----------------

__global__ void deg_kernel(const int* __restrict__ dst, int* __restrict__ deg) {
    int e = blockIdx.x * blockDim.x + threadIdx.x;
    if (e < N_EDGES) atomicAdd(&deg[dst[e]], 1);
}

__global__ void dinv_kernel(const int* __restrict__ deg, float* __restrict__ dinv) {
    int i = blockIdx.x * blockDim.x + threadIdx.x;
    if (i < N_NODES) dinv[i] = rsqrtf((float)deg[i] + 1.0f);
}

__global__ void scan1_kernel(const int* __restrict__ deg, int* __restrict__ excl,
                             int* __restrict__ bsum) {
    __shared__ int sh[1024];
    int tid = threadIdx.x;
    int gid = blockIdx.x * 1024 + tid;   // N = 100*1024 exactly
    int v = deg[gid];
    sh[tid] = v;
    __syncthreads();
    for (int off = 1; off < 1024; off <<= 1) {
        int t = (tid >= off) ? sh[tid - off] : 0;
        __syncthreads();
        sh[tid] += t;
        __syncthreads();
    }
    excl[gid] = sh[tid] - v;
    if (tid == 1023) bsum[blockIdx.x] = sh[tid];
}

__global__ void scan2_kernel(int* __restrict__ bsum) {  // 100 entries, 1 block of 128
    __shared__ int sh[128];
    int tid = threadIdx.x;
    int v = (tid < 100) ? bsum[tid] : 0;
    sh[tid] = v;
    __syncthreads();
    for (int off = 1; off < 128; off <<= 1) {
        int t = (tid >= off) ? sh[tid - off] : 0;
        __syncthreads();
        sh[tid] += t;
        __syncthreads();
    }
    if (tid < 100) bsum[tid] = sh[tid] - v;
}

__global__ void scan3_kernel(const int* __restrict__ excl, const int* __restrict__ bsum,
                             int* __restrict__ offs, int* __restrict__ cursor) {
    int gid = blockIdx.x * blockDim.x + threadIdx.x;
    if (gid < N_NODES) {
        int o = excl[gid] + bsum[gid >> 10];
        offs[gid] = o;
        cursor[gid] = o;
    }
    if (gid == 0) offs[N_NODES] = N_EDGES;
}

__global__ void fill_kernel(const int* __restrict__ src, const int* __restrict__ dst,
                            int* __restrict__ cursor, int* __restrict__ csr_src,
                            float* __restrict__ csr_w, const float* __restrict__ dinv) {
    int e = blockIdx.x * blockDim.x + threadIdx.x;
    if (e >= N_EDGES) return;
    int s = src[e], d = dst[e];
    int pos = atomicAdd(&cursor[d], 1);
    csr_src[pos] = s;
    csr_w[pos] = dinv[s] * dinv[d];
}

// ---------------- to_dense_batch row mapping ----------------

__global__ void start_kernel(const int* __restrict__ batch, int* __restrict__ startb) {
    int i = blockIdx.x * blockDim.x + threadIdx.x;
    if (i >= N_NODES) return;
    if (i == 0 || batch[i] != batch[i - 1]) startb[batch[i]] = i;
}

__global__ void rowmap_kernel(const int* __restrict__ batch, const int* __restrict__ startb,
                              const int* __restrict__ pmax, int* __restrict__ rowmap) {
    int i = blockIdx.x * blockDim.x + threadIdx.x;
    if (i >= N_NODES) return;
    int b = batch[i];
    int mx = *pmax;
    int pos = i - startb[b];
    rowmap[i] = (pos < mx) ? (b * mx + pos) : -1;
}

// ---------------- weight prep: WT[c][k] = bf16(W[k][c]), zero-padded ----------------

__global__ void prep_w_kernel(const float* __restrict__ W, const float* __restrict__ b,
                              int K, int Nc, int Kp, int Na,
                              __hip_bfloat16* __restrict__ WT, float* __restrict__ bp) {
    int i = blockIdx.x * blockDim.x + threadIdx.x;
    int total = Na * Kp;
    if (i < total) {
        int c = i / Kp, k = i - c * Kp;
        float v = (c < Nc && k < K) ? W[k * Nc + c] : 0.0f;
        WT[i] = __float2bfloat16(v);
    }
    if (i < Na) bp[i] = (i < Nc) ? b[i] : 0.0f;
}

// ---------------- aggregation ----------------
// out[n][:] = dinv[n]^2 * H[n][:] + sum_{e: dst=n} w_e * H[src_e][:]   (bf16 out, fp32 accum)

__global__ void agg_f32_kernel(const float* __restrict__ X,
                               const int* __restrict__ offs, const int* __restrict__ csr_src,
                               const float* __restrict__ csr_w, const float* __restrict__ dinv,
                               __hip_bfloat16* __restrict__ out) {
    // X: [N,78] fp32 ; out: [N,96] bf16 (pad zeros)
    int node = (blockIdx.x * blockDim.x + threadIdx.x) >> 6;
    int lane = threadIdx.x & 63;
    if (node >= N_NODES) return;
    float di = dinv[node];
    float sw = di * di;
    int e0 = offs[node], e1 = offs[node + 1];
    int f = lane * 2;
    float ax = 0.0f, ay = 0.0f;
    if (f < 78) {
        float2 h = *(const float2*)(X + (size_t)node * 78 + f);
        ax = sw * h.x;
        ay = sw * h.y;
        for (int j = e0; j < e1; ++j) {
            int s = csr_src[j];
            float w = csr_w[j];
            float2 hv = *(const float2*)(X + (size_t)s * 78 + f);
            ax += w * hv.x;
            ay += w * hv.y;
        }
    }
    if (f < 96) {
        __hip_bfloat162 r;
        r.x = __float2bfloat16(ax);
        r.y = __float2bfloat16(ay);
        *(__hip_bfloat162*)(out + (size_t)node * 96 + f) = r;
    }
}

__global__ void agg_bf16_kernel(const __hip_bfloat16* __restrict__ H, int ld,
                                const int* __restrict__ offs, const int* __restrict__ csr_src,
                                const float* __restrict__ csr_w, const float* __restrict__ dinv,
                                __hip_bfloat16* __restrict__ out) {
    int node = (blockIdx.x * blockDim.x + threadIdx.x) >> 6;
    int lane = threadIdx.x & 63;
    if (node >= N_NODES) return;
    float di = dinv[node];
    float sw = di * di;
    int e0 = offs[node], e1 = offs[node + 1];
    for (int f0 = 0; f0 < ld; f0 += 128) {
        int f = f0 + lane * 2;
        if (f < ld) {
            __hip_bfloat162 h = *(const __hip_bfloat162*)(H + (size_t)node * ld + f);
            float ax = sw * __bfloat162float(h.x);
            float ay = sw * __bfloat162float(h.y);
            for (int j = e0; j < e1; ++j) {
                int s = csr_src[j];
                float w = csr_w[j];
                __hip_bfloat162 hv = *(const __hip_bfloat162*)(H + (size_t)s * ld + f);
                ax += w * __bfloat162float(hv.x);
                ay += w * __bfloat162float(hv.y);
            }
            __hip_bfloat162 r;
            r.x = __float2bfloat16(ax);
            r.y = __float2bfloat16(ay);
            *(__hip_bfloat162*)(out + (size_t)node * ld + f) = r;
        }
    }
}

// ---------------- bf16 MFMA GEMM: C = A[102400, Kp] @ WT^T + bias ----------------
// A: bf16 [N, lda], k-major. WT: bf16 [ntiles*128, lda] (row c = output col c), k-major.
// Tile: 128 rows x 128 cols, BK=32. 4 waves, each 64x64 (4x4 frags of 16x16).
// LDS rows are 64B; phys slot = logical_slot XOR (row&3) (both-sides swizzle).

__global__ __launch_bounds__(256) void mfma_gemm_kernel(
    const __hip_bfloat16* __restrict__ A, int lda,
    const __hip_bfloat16* __restrict__ WT,
    const float* __restrict__ biasp, int nsteps,
    void* __restrict__ Cout, int ldc, int ccols,
    const int* __restrict__ rowmap, int relu) {
    __shared__ __align__(16) char lds[32768];  // [2 bufs][A 8KB | B 8KB]

    const int tid = threadIdx.x;
    const int lane = tid & 63;
    const int wid = tid >> 6;
    const int wr = wid >> 1, wc = wid & 1;
    const int r0 = blockIdx.y * 128;
    const int c0 = blockIdx.x * 128;

    // ---- staging thread mapping: thread covers rows {t/4, t/4+64}, 16B slot t&3 ----
    const int strow = tid >> 2;
    const int sl16 = (tid & 3) << 4;
    const int ssw = (strow & 3) << 4;
    const char* arow0 = (const char*)(A + (size_t)(r0 + strow) * lda);
    const char* arow1 = (const char*)(A + (size_t)(r0 + strow + 64) * lda);
    const char* brow0 = (const char*)(WT + (size_t)(c0 + strow) * lda);
    const char* brow1 = (const char*)(WT + (size_t)(c0 + strow + 64) * lda);
    const int wA0 = strow * 64 + (sl16 ^ ssw);
    const int wA1 = (strow + 64) * 64 + (sl16 ^ ssw);
    const int wB0 = 8192 + wA0;
    const int wB1 = 8192 + wA1;

    // ---- fragment read offsets ----
    const int frow = lane & 15;
    const int fswz = ((lane >> 4) << 4) ^ ((frow & 3) << 4);
    int aoff[4], boff[4];
#pragma unroll
    for (int m = 0; m < 4; ++m) aoff[m] = (wr * 64 + m * 16 + frow) * 64 + fswz;
#pragma unroll
    for (int n = 0; n < 4; ++n) boff[n] = 8192 + (wc * 64 + n * 16 + frow) * 64 + fswz;

    f32x4 acc[4][4];
#pragma unroll
    for (int m = 0; m < 4; ++m)
#pragma unroll
        for (int n = 0; n < 4; ++n) {
            f32x4 z = {0.0f, 0.0f, 0.0f, 0.0f};
            acc[m][n] = z;
        }

    int4 sA0, sA1, sB0, sB1;
#define LOADT(kt)                                                      \
    do {                                                               \
        size_t kb = (size_t)(kt)*64 + sl16;                            \
        sA0 = *(const int4*)(arow0 + kb);                              \
        sA1 = *(const int4*)(arow1 + kb);                              \
        sB0 = *(const int4*)(brow0 + kb);                              \
        sB1 = *(const int4*)(brow1 + kb);                              \
    } while (0)

    LOADT(0);
    int cur = 0;
    for (int t = 0; t < nsteps; ++t) {
        char* base = lds + (cur << 14);
        *(int4*)(base + wA0) = sA0;
        *(int4*)(base + wA1) = sA1;
        *(int4*)(base + wB0) = sB0;
        *(int4*)(base + wB1) = sB1;
        if (t + 1 < nsteps) LOADT(t + 1);  // prefetch next tile (latency hides under MFMA)
        asm volatile("s_waitcnt lgkmcnt(0)" ::: "memory");
        __builtin_amdgcn_s_barrier();
        __builtin_amdgcn_sched_barrier(0);
        const char* cb = lds + (cur << 14);
        short8 af[4], bfr[4];
#pragma unroll
        for (int m = 0; m < 4; ++m) af[m] = *(const short8*)(cb + aoff[m]);
#pragma unroll
        for (int n = 0; n < 4; ++n) bfr[n] = *(const short8*)(cb + boff[n]);
#pragma unroll
        for (int m = 0; m < 4; ++m)
#pragma unroll
            for (int n = 0; n < 4; ++n)
                acc[m][n] = __builtin_amdgcn_mfma_f32_16x16x32_bf16(af[m], bfr[n], acc[m][n], 0, 0, 0);
        asm volatile("s_waitcnt lgkmcnt(0)" ::: "memory");
        __builtin_amdgcn_s_barrier();
        __builtin_amdgcn_sched_barrier(0);
        cur ^= 1;
    }
#undef LOADT

    // ---- epilogue: C frag layout col=lane&15, row=(lane>>4)*4+j ----
    const int crow0 = r0 + wr * 64 + ((lane >> 4) << 2);
    const int ccol0 = c0 + wc * 64 + (lane & 15);
#pragma unroll
    for (int n = 0; n < 4; ++n) {
        int col = ccol0 + n * 16;
        if (col >= ccols) continue;
        float bv = biasp[col];
#pragma unroll
        for (int m = 0; m < 4; ++m) {
#pragma unroll
            for (int j = 0; j < 4; ++j) {
                int row = crow0 + m * 16 + j;
                float v = acc[m][n][j] + bv;
                if (relu) v = fmaxf(v, 0.0f);
                if (rowmap) {
                    int drow = rowmap[row];
                    if (drow >= 0) ((float*)Cout)[(size_t)drow * ldc + col] = v;
                } else {
                    ((__hip_bfloat16*)Cout)[(size_t)row * ldc + col] = __float2bfloat16(v);
                }
            }
        }
    }
}

// ---------------- launch ----------------

static inline char* align256(char* p) {
    return (char*)(((uintptr_t)p + 255) & ~(uintptr_t)255);
}

extern "C" void kernel_launch(void* const* d_in, const int* in_sizes, int n_in,
                              void* d_out, int out_size, void* d_ws, size_t ws_size,
                              hipStream_t stream) {
    const int N = N_NODES, E = N_EDGES;
    const float* x = (const float*)d_in[0];
    const int* ei = (const int*)d_in[1];
    const int* src = ei;
    const int* dst = ei + E;
    const int* batch = (const int*)d_in[2];
    const int* pmax = (const int*)d_in[3];
    const float* W1 = (const float*)d_in[4];
    const float* b1 = (const float*)d_in[5];
    const float* W2 = (const float*)d_in[6];
    const float* b2 = (const float*)d_in[7];
    const float* W3 = (const float*)d_in[8];
    const float* b3 = (const float*)d_in[9];
    const float* Wfc = (const float*)d_in[10];
    const float* bfc = (const float*)d_in[11];
    float* out = (float*)d_out;

    // workspace carve (~137 MB)
    char* p = (char*)d_ws;
    float* dinv = (float*)p;          p = align256(p + (size_t)N * 4);
    int* deg = (int*)p;               p = align256(p + (size_t)N * 4);
    int* offs = (int*)p;              p = align256(p + (size_t)(N + 1) * 4);
    int* cursor = (int*)p;            p = align256(p + (size_t)N * 4);
    int* excl = (int*)p;              p = align256(p + (size_t)N * 4);
    int* bsum = (int*)p;              p = align256(p + 128 * 4);
    int* csr_src = (int*)p;           p = align256(p + (size_t)E * 4);
    float* csr_w = (float*)p;         p = align256(p + (size_t)E * 4);
    int* startb = (int*)p;            p = align256(p + (size_t)N_GRAPHS * 4);
    int* rowmap = (int*)p;            p = align256(p + (size_t)N * 4);
    __hip_bfloat16* WT1 = (__hip_bfloat16*)p;  p = align256(p + 128 * 96 * 2);
    float* b1p = (float*)p;           p = align256(p + 128 * 4);
    __hip_bfloat16* WT2 = (__hip_bfloat16*)p;  p = align256(p + 256 * 96 * 2);
    float* b2p = (float*)p;           p = align256(p + 256 * 4);
    __hip_bfloat16* WT3 = (__hip_bfloat16*)p;  p = align256(p + 384 * 160 * 2);
    float* b3p = (float*)p;           p = align256(p + 384 * 4);
    __hip_bfloat16* WTF = (__hip_bfloat16*)p;  p = align256(p + 256 * 320 * 2);
    float* bFp = (float*)p;           p = align256(p + 256 * 4);
    __hip_bfloat16* bufAgg = (__hip_bfloat16*)p;  p = align256(p + (size_t)N * 320 * 2);
    __hip_bfloat16* bufH = (__hip_bfloat16*)p;    p = align256(p + (size_t)N * 320 * 2);

    // degree + CSR
    hipMemsetAsync(deg, 0, (size_t)N * 4, stream);
    deg_kernel<<<(E + 255) / 256, 256, 0, stream>>>(dst, deg);
    dinv_kernel<<<(N + 255) / 256, 256, 0, stream>>>(deg, dinv);
    scan1_kernel<<<100, 1024, 0, stream>>>(deg, excl, bsum);
    scan2_kernel<<<1, 128, 0, stream>>>(bsum);
    scan3_kernel<<<(N + 255) / 256, 256, 0, stream>>>(excl, bsum, offs, cursor);
    fill_kernel<<<(E + 255) / 256, 256, 0, stream>>>(src, dst, cursor, csr_src, csr_w, dinv);

    // dense-batch mapping
    start_kernel<<<(N + 255) / 256, 256, 0, stream>>>(batch, startb);
    rowmap_kernel<<<(N + 255) / 256, 256, 0, stream>>>(batch, startb, pmax, rowmap);

    // weight prep (bf16, transposed, padded)
    prep_w_kernel<<<(128 * 96 + 255) / 256, 256, 0, stream>>>(W1, b1, 78, 78, 96, 128, WT1, b1p);
    prep_w_kernel<<<(256 * 96 + 255) / 256, 256, 0, stream>>>(W2, b2, 78, 156, 96, 256, WT2, b2p);
    prep_w_kernel<<<(384 * 160 + 255) / 256, 256, 0, stream>>>(W3, b3, 156, 312, 160, 384, WT3, b3p);
    prep_w_kernel<<<(256 * 320 + 255) / 256, 256, 0, stream>>>(Wfc, bfc, 312, 200, 320, 256, WTF, bFp);

    // Layer 1: agg(x) -> [N,96] bf16 ; gemm -> h1 [N,96] bf16
    agg_f32_kernel<<<N / 4, 256, 0, stream>>>(x, offs, csr_src, csr_w, dinv, bufAgg);
    mfma_gemm_kernel<<<dim3(1, N / 128), 256, 0, stream>>>(
        bufAgg, 96, WT1, b1p, 3, bufH, 96, 96, nullptr, 1);

    // Layer 2
    agg_bf16_kernel<<<N / 4, 256, 0, stream>>>(bufH, 96, offs, csr_src, csr_w, dinv, bufAgg);
    mfma_gemm_kernel<<<dim3(2, N / 128), 256, 0, stream>>>(
        bufAgg, 96, WT2, b2p, 3, bufH, 160, 160, nullptr, 1);

    // Layer 3
    agg_bf16_kernel<<<N / 4, 256, 0, stream>>>(bufH, 160, offs, csr_src, csr_w, dinv, bufAgg);
    mfma_gemm_kernel<<<dim3(3, N / 128), 256, 0, stream>>>(
        bufAgg, 160, WT3, b3p, 5, bufH, 320, 320, nullptr, 1);

    // FC + fused to_dense_batch scatter (fp32 out)
    hipMemsetAsync(out, 0, (size_t)out_size * sizeof(float), stream);
    mfma_gemm_kernel<<<dim3(2, N / 128), 256, 0, stream>>>(
        bufH, 320, WTF, bFp, 10, out, 200, 200, rowmap, 0);
}

// Round 3
// 341.016 us; speedup vs baseline: 3.9073x; 1.3122x over previous
//
#include <hip/hip_runtime.h>
#include <hip/hip_bf16.h>
#include <stdint.h>

#define N_NODES 102400
#define N_EDGES 409600
#define N_GRAPHS 2048
#define MAXN 64

typedef __attribute__((ext_vector_type(8))) short short8;
typedef __attribute__((ext_vector_type(4))) float f32x4;

static __device__ __forceinline__ float bfu2f(unsigned short u) {
    union { unsigned int i; float f; } v;
    v.i = ((unsigned int)u) << 16;
    return v.f;
}
static __device__ __forceinline__ unsigned short f2bfu(float f) {
    __hip_bfloat16 h = __float2bfloat16(f);
    return *reinterpret_cast<unsigned short*>(&h);
}

// ---------------- degree / CSR build ----------------

__global__ void deg_kernel(const int* __restrict__ dst, int* __restrict__ deg) {
    int e = blockIdx.x * blockDim.x + threadIdx.x;
    if (e < N_EDGES) atomicAdd(&deg[dst[e]], 1);
}

__global__ void dinv_kernel(const int* __restrict__ deg, float* __restrict__ dinv) {
    int i = blockIdx.x * blockDim.x + threadIdx.x;
    if (i < N_NODES) dinv[i] = rsqrtf((float)deg[i] + 1.0f);
}

__global__ void scan1_kernel(const int* __restrict__ deg, int* __restrict__ excl,
                             int* __restrict__ bsum) {
    __shared__ int sh[1024];
    int tid = threadIdx.x;
    int gid = blockIdx.x * 1024 + tid;   // N = 100*1024 exactly
    int v = deg[gid];
    sh[tid] = v;
    __syncthreads();
    for (int off = 1; off < 1024; off <<= 1) {
        int t = (tid >= off) ? sh[tid - off] : 0;
        __syncthreads();
        sh[tid] += t;
        __syncthreads();
    }
    excl[gid] = sh[tid] - v;
    if (tid == 1023) bsum[blockIdx.x] = sh[tid];
}

__global__ void scan2_kernel(int* __restrict__ bsum) {  // 100 entries
    __shared__ int sh[128];
    int tid = threadIdx.x;
    int v = (tid < 100) ? bsum[tid] : 0;
    sh[tid] = v;
    __syncthreads();
    for (int off = 1; off < 128; off <<= 1) {
        int t = (tid >= off) ? sh[tid - off] : 0;
        __syncthreads();
        sh[tid] += t;
        __syncthreads();
    }
    if (tid < 100) bsum[tid] = sh[tid] - v;
}

__global__ void scan3_kernel(const int* __restrict__ excl, const int* __restrict__ bsum,
                             int* __restrict__ offs, int* __restrict__ cursor) {
    int gid = blockIdx.x * blockDim.x + threadIdx.x;
    if (gid < N_NODES) {
        int o = excl[gid] + bsum[gid >> 10];
        offs[gid] = o;
        cursor[gid] = o;
    }
    if (gid == 0) offs[N_NODES] = N_EDGES;
}

__global__ void fill_kernel(const int* __restrict__ src, const int* __restrict__ dst,
                            int* __restrict__ cursor, int* __restrict__ csr_src,
                            float* __restrict__ csr_w, const float* __restrict__ dinv) {
    int e = blockIdx.x * blockDim.x + threadIdx.x;
    if (e >= N_EDGES) return;
    int s = src[e], d = dst[e];
    int pos = atomicAdd(&cursor[d], 1);
    csr_src[pos] = s;
    csr_w[pos] = dinv[s] * dinv[d];
}

// ---------------- to_dense_batch row mapping ----------------

__global__ void start_kernel(const int* __restrict__ batch, int* __restrict__ startb) {
    int i = blockIdx.x * blockDim.x + threadIdx.x;
    if (i >= N_NODES) return;
    if (i == 0 || batch[i] != batch[i - 1]) startb[batch[i]] = i;
    if (i == 0) startb[N_GRAPHS] = N_NODES;
}

__global__ void rowmap_kernel(const int* __restrict__ batch, const int* __restrict__ startb,
                              const int* __restrict__ pmax, int* __restrict__ rowmap) {
    int i = blockIdx.x * blockDim.x + threadIdx.x;
    if (i >= N_NODES) return;
    int b = batch[i];
    int mx = *pmax;
    int pos = i - startb[b];
    rowmap[i] = (pos < mx) ? (b * mx + pos) : -1;
}

// zero only the padding rows of the dense output: rows (b, pos) with pos >= count[b]
__global__ void padzero_kernel(const int* __restrict__ startb, float* __restrict__ out) {
    int b = blockIdx.y;
    int idx = blockIdx.x * blockDim.x + threadIdx.x;  // covers MAXN*100 float2
    int pos = idx / 100;
    int f = idx - pos * 100;
    int count = startb[b + 1] - startb[b];
    if (pos >= count && pos < MAXN) {
        float2 z = {0.0f, 0.0f};
        *(float2*)(out + ((size_t)b * MAXN + pos) * 200 + f * 2) = z;
    }
}

// ---------------- weight prep ----------------

__global__ void prep_w_kernel(const float* __restrict__ W, const float* __restrict__ b,
                              int K, int Nc, int Kp, int Na,
                              __hip_bfloat16* __restrict__ WT, float* __restrict__ bp) {
    int i = blockIdx.x * blockDim.x + threadIdx.x;
    int total = Na * Kp;
    if (i < total) {
        int c = i / Kp, k = i - c * Kp;
        float v = (c < Nc && k < K) ? W[k * Nc + c] : 0.0f;
        WT[i] = __float2bfloat16(v);
    }
    if (i < Na) bp[i] = (i < Nc) ? b[i] : 0.0f;
}

// ---------------- aggregation v2: thread-per-(node, 8B chunk), 4-way edge unroll ----------

// Layer 1: X fp32 [N,78] -> out bf16 [N,96]. C=48 chunks of 2 cols.
__global__ __launch_bounds__(256) void agg_f32_v2(
    const float* __restrict__ X,
    const int* __restrict__ offs, const int* __restrict__ csr_src,
    const float* __restrict__ csr_w, const float* __restrict__ dinv,
    __hip_bfloat16* __restrict__ out) {
    constexpr int C = 48;
    int idx = blockIdx.x * blockDim.x + threadIdx.x;
    if (idx >= N_NODES * C) return;
    int node = idx / C;
    int c = idx - node * C;
    int col = c * 2;
    float a0 = 0.0f, a1 = 0.0f;
    if (col < 78) {
        float di = dinv[node];
        float sw = di * di;
        const float* Xr = X + (size_t)node * 78 + col;
        float2 h = *(const float2*)Xr;
        a0 = sw * h.x;
        a1 = sw * h.y;
        int e0 = offs[node], e1 = offs[node + 1];
        int j = e0;
        for (; j + 4 <= e1; j += 4) {
            int s0 = csr_src[j], s1 = csr_src[j + 1], s2 = csr_src[j + 2], s3 = csr_src[j + 3];
            float w0 = csr_w[j], w1 = csr_w[j + 1], w2 = csr_w[j + 2], w3 = csr_w[j + 3];
            float2 v0 = *(const float2*)(X + (size_t)s0 * 78 + col);
            float2 v1 = *(const float2*)(X + (size_t)s1 * 78 + col);
            float2 v2 = *(const float2*)(X + (size_t)s2 * 78 + col);
            float2 v3 = *(const float2*)(X + (size_t)s3 * 78 + col);
            a0 += w0 * v0.x + w1 * v1.x + w2 * v2.x + w3 * v3.x;
            a1 += w0 * v0.y + w1 * v1.y + w2 * v2.y + w3 * v3.y;
        }
        for (; j < e1; ++j) {
            int s = csr_src[j];
            float w = csr_w[j];
            float2 v = *(const float2*)(X + (size_t)s * 78 + col);
            a0 += w * v.x;
            a1 += w * v.y;
        }
    }
    __hip_bfloat162 r;
    r.x = __float2bfloat16(a0);
    r.y = __float2bfloat16(a1);
    *(__hip_bfloat162*)(out + (size_t)node * 96 + col) = r;
}

// Layers 2/3: H bf16 [N,LD] -> out bf16 [N,LD]. C=LD/4 chunks of 4 cols.
template <int LD>
__global__ __launch_bounds__(256) void agg_bf16_v2(
    const __hip_bfloat16* __restrict__ H,
    const int* __restrict__ offs, const int* __restrict__ csr_src,
    const float* __restrict__ csr_w, const float* __restrict__ dinv,
    __hip_bfloat16* __restrict__ out) {
    constexpr int C = LD / 4;
    int idx = blockIdx.x * blockDim.x + threadIdx.x;
    if (idx >= N_NODES * C) return;
    int node = idx / C;
    int c = idx - node * C;
    const unsigned short* Hu = (const unsigned short*)H;
    size_t rowoff = (size_t)node * LD + c * 4;
    float di = dinv[node];
    float sw = di * di;
    ushort4 h = *(const ushort4*)(Hu + rowoff);
    float a0 = sw * bfu2f(h.x), a1 = sw * bfu2f(h.y), a2 = sw * bfu2f(h.z), a3 = sw * bfu2f(h.w);
    int e0 = offs[node], e1 = offs[node + 1];
    int j = e0;
    for (; j + 4 <= e1; j += 4) {
        int s0 = csr_src[j], s1 = csr_src[j + 1], s2 = csr_src[j + 2], s3 = csr_src[j + 3];
        float w0 = csr_w[j], w1 = csr_w[j + 1], w2 = csr_w[j + 2], w3 = csr_w[j + 3];
        ushort4 v0 = *(const ushort4*)(Hu + (size_t)s0 * LD + c * 4);
        ushort4 v1 = *(const ushort4*)(Hu + (size_t)s1 * LD + c * 4);
        ushort4 v2 = *(const ushort4*)(Hu + (size_t)s2 * LD + c * 4);
        ushort4 v3 = *(const ushort4*)(Hu + (size_t)s3 * LD + c * 4);
        a0 += w0 * bfu2f(v0.x) + w1 * bfu2f(v1.x) + w2 * bfu2f(v2.x) + w3 * bfu2f(v3.x);
        a1 += w0 * bfu2f(v0.y) + w1 * bfu2f(v1.y) + w2 * bfu2f(v2.y) + w3 * bfu2f(v3.y);
        a2 += w0 * bfu2f(v0.z) + w1 * bfu2f(v1.z) + w2 * bfu2f(v2.z) + w3 * bfu2f(v3.z);
        a3 += w0 * bfu2f(v0.w) + w1 * bfu2f(v1.w) + w2 * bfu2f(v2.w) + w3 * bfu2f(v3.w);
    }
    for (; j < e1; ++j) {
        int s = csr_src[j];
        float w = csr_w[j];
        ushort4 v = *(const ushort4*)(Hu + (size_t)s * LD + c * 4);
        a0 += w * bfu2f(v.x);
        a1 += w * bfu2f(v.y);
        a2 += w * bfu2f(v.z);
        a3 += w * bfu2f(v.w);
    }
    ushort4 r;
    r.x = f2bfu(a0);
    r.y = f2bfu(a1);
    r.z = f2bfu(a2);
    r.w = f2bfu(a3);
    *(ushort4*)((unsigned short*)out + rowoff) = r;
}

// ---------------- bf16 MFMA GEMM (unchanged structure) ----------------

__global__ __launch_bounds__(256) void mfma_gemm_kernel(
    const __hip_bfloat16* __restrict__ A, int lda,
    const __hip_bfloat16* __restrict__ WT,
    const float* __restrict__ biasp, int nsteps,
    void* __restrict__ Cout, int ldc, int ccols,
    const int* __restrict__ rowmap, int relu) {
    __shared__ __align__(16) char lds[32768];

    const int tid = threadIdx.x;
    const int lane = tid & 63;
    const int wid = tid >> 6;
    const int wr = wid >> 1, wc = wid & 1;
    const int r0 = blockIdx.y * 128;
    const int c0 = blockIdx.x * 128;

    const int strow = tid >> 2;
    const int sl16 = (tid & 3) << 4;
    const int ssw = (strow & 3) << 4;
    const char* arow0 = (const char*)(A + (size_t)(r0 + strow) * lda);
    const char* arow1 = (const char*)(A + (size_t)(r0 + strow + 64) * lda);
    const char* brow0 = (const char*)(WT + (size_t)(c0 + strow) * lda);
    const char* brow1 = (const char*)(WT + (size_t)(c0 + strow + 64) * lda);
    const int wA0 = strow * 64 + (sl16 ^ ssw);
    const int wA1 = (strow + 64) * 64 + (sl16 ^ ssw);
    const int wB0 = 8192 + wA0;
    const int wB1 = 8192 + wA1;

    const int frow = lane & 15;
    const int fswz = ((lane >> 4) << 4) ^ ((frow & 3) << 4);
    int aoff[4], boff[4];
#pragma unroll
    for (int m = 0; m < 4; ++m) aoff[m] = (wr * 64 + m * 16 + frow) * 64 + fswz;
#pragma unroll
    for (int n = 0; n < 4; ++n) boff[n] = 8192 + (wc * 64 + n * 16 + frow) * 64 + fswz;

    f32x4 acc[4][4];
#pragma unroll
    for (int m = 0; m < 4; ++m)
#pragma unroll
        for (int n = 0; n < 4; ++n) {
            f32x4 z = {0.0f, 0.0f, 0.0f, 0.0f};
            acc[m][n] = z;
        }

    int4 sA0, sA1, sB0, sB1;
#define LOADT(kt)                                                      \
    do {                                                               \
        size_t kb = (size_t)(kt)*64 + sl16;                            \
        sA0 = *(const int4*)(arow0 + kb);                              \
        sA1 = *(const int4*)(arow1 + kb);                              \
        sB0 = *(const int4*)(brow0 + kb);                              \
        sB1 = *(const int4*)(brow1 + kb);                              \
    } while (0)

    LOADT(0);
    int cur = 0;
    for (int t = 0; t < nsteps; ++t) {
        char* base = lds + (cur << 14);
        *(int4*)(base + wA0) = sA0;
        *(int4*)(base + wA1) = sA1;
        *(int4*)(base + wB0) = sB0;
        *(int4*)(base + wB1) = sB1;
        if (t + 1 < nsteps) LOADT(t + 1);
        asm volatile("s_waitcnt lgkmcnt(0)" ::: "memory");
        __builtin_amdgcn_s_barrier();
        __builtin_amdgcn_sched_barrier(0);
        const char* cb = lds + (cur << 14);
        short8 af[4], bfr[4];
#pragma unroll
        for (int m = 0; m < 4; ++m) af[m] = *(const short8*)(cb + aoff[m]);
#pragma unroll
        for (int n = 0; n < 4; ++n) bfr[n] = *(const short8*)(cb + boff[n]);
#pragma unroll
        for (int m = 0; m < 4; ++m)
#pragma unroll
            for (int n = 0; n < 4; ++n)
                acc[m][n] = __builtin_amdgcn_mfma_f32_16x16x32_bf16(af[m], bfr[n], acc[m][n], 0, 0, 0);
        asm volatile("s_waitcnt lgkmcnt(0)" ::: "memory");
        __builtin_amdgcn_s_barrier();
        __builtin_amdgcn_sched_barrier(0);
        cur ^= 1;
    }
#undef LOADT

    const int crow0 = r0 + wr * 64 + ((lane >> 4) << 2);
    const int ccol0 = c0 + wc * 64 + (lane & 15);
#pragma unroll
    for (int n = 0; n < 4; ++n) {
        int col = ccol0 + n * 16;
        if (col >= ccols) continue;
        float bv = biasp[col];
#pragma unroll
        for (int m = 0; m < 4; ++m) {
#pragma unroll
            for (int j = 0; j < 4; ++j) {
                int row = crow0 + m * 16 + j;
                float v = acc[m][n][j] + bv;
                if (relu) v = fmaxf(v, 0.0f);
                if (rowmap) {
                    int drow = rowmap[row];
                    if (drow >= 0) ((float*)Cout)[(size_t)drow * ldc + col] = v;
                } else {
                    ((__hip_bfloat16*)Cout)[(size_t)row * ldc + col] = __float2bfloat16(v);
                }
            }
        }
    }
}

// ---------------- launch ----------------

static inline char* align256(char* p) {
    return (char*)(((uintptr_t)p + 255) & ~(uintptr_t)255);
}

extern "C" void kernel_launch(void* const* d_in, const int* in_sizes, int n_in,
                              void* d_out, int out_size, void* d_ws, size_t ws_size,
                              hipStream_t stream) {
    const int N = N_NODES, E = N_EDGES;
    const float* x = (const float*)d_in[0];
    const int* ei = (const int*)d_in[1];
    const int* src = ei;
    const int* dst = ei + E;
    const int* batch = (const int*)d_in[2];
    const int* pmax = (const int*)d_in[3];
    const float* W1 = (const float*)d_in[4];
    const float* b1 = (const float*)d_in[5];
    const float* W2 = (const float*)d_in[6];
    const float* b2 = (const float*)d_in[7];
    const float* W3 = (const float*)d_in[8];
    const float* b3 = (const float*)d_in[9];
    const float* Wfc = (const float*)d_in[10];
    const float* bfc = (const float*)d_in[11];
    float* out = (float*)d_out;

    char* p = (char*)d_ws;
    float* dinv = (float*)p;          p = align256(p + (size_t)N * 4);
    int* deg = (int*)p;               p = align256(p + (size_t)N * 4);
    int* offs = (int*)p;              p = align256(p + (size_t)(N + 1) * 4);
    int* cursor = (int*)p;            p = align256(p + (size_t)N * 4);
    int* excl = (int*)p;              p = align256(p + (size_t)N * 4);
    int* bsum = (int*)p;              p = align256(p + 128 * 4);
    int* csr_src = (int*)p;           p = align256(p + (size_t)E * 4);
    float* csr_w = (float*)p;         p = align256(p + (size_t)E * 4);
    int* startb = (int*)p;            p = align256(p + (size_t)(N_GRAPHS + 1) * 4);
    int* rowmap = (int*)p;            p = align256(p + (size_t)N * 4);
    __hip_bfloat16* WT1 = (__hip_bfloat16*)p;  p = align256(p + 128 * 96 * 2);
    float* b1p = (float*)p;           p = align256(p + 128 * 4);
    __hip_bfloat16* WT2 = (__hip_bfloat16*)p;  p = align256(p + 256 * 96 * 2);
    float* b2p = (float*)p;           p = align256(p + 256 * 4);
    __hip_bfloat16* WT3 = (__hip_bfloat16*)p;  p = align256(p + 384 * 160 * 2);
    float* b3p = (float*)p;           p = align256(p + 384 * 4);
    __hip_bfloat16* WTF = (__hip_bfloat16*)p;  p = align256(p + 256 * 320 * 2);
    float* bFp = (float*)p;           p = align256(p + 256 * 4);
    __hip_bfloat16* bufAgg = (__hip_bfloat16*)p;  p = align256(p + (size_t)N * 320 * 2);
    __hip_bfloat16* bufH = (__hip_bfloat16*)p;    p = align256(p + (size_t)N * 320 * 2);

    // degree + CSR
    hipMemsetAsync(deg, 0, (size_t)N * 4, stream);
    deg_kernel<<<(E + 255) / 256, 256, 0, stream>>>(dst, deg);
    dinv_kernel<<<(N + 255) / 256, 256, 0, stream>>>(deg, dinv);
    scan1_kernel<<<100, 1024, 0, stream>>>(deg, excl, bsum);
    scan2_kernel<<<1, 128, 0, stream>>>(bsum);
    scan3_kernel<<<(N + 255) / 256, 256, 0, stream>>>(excl, bsum, offs, cursor);
    fill_kernel<<<(E + 255) / 256, 256, 0, stream>>>(src, dst, cursor, csr_src, csr_w, dinv);

    // dense-batch mapping
    start_kernel<<<(N + 255) / 256, 256, 0, stream>>>(batch, startb);
    rowmap_kernel<<<(N + 255) / 256, 256, 0, stream>>>(batch, startb, pmax, rowmap);

    // weight prep
    prep_w_kernel<<<(128 * 96 + 255) / 256, 256, 0, stream>>>(W1, b1, 78, 78, 96, 128, WT1, b1p);
    prep_w_kernel<<<(256 * 96 + 255) / 256, 256, 0, stream>>>(W2, b2, 78, 156, 96, 256, WT2, b2p);
    prep_w_kernel<<<(384 * 160 + 255) / 256, 256, 0, stream>>>(W3, b3, 156, 312, 160, 384, WT3, b3p);
    prep_w_kernel<<<(256 * 320 + 255) / 256, 256, 0, stream>>>(Wfc, bfc, 312, 200, 320, 256, WTF, bFp);

    // Layer 1
    agg_f32_v2<<<(N * 48 + 255) / 256, 256, 0, stream>>>(x, offs, csr_src, csr_w, dinv, bufAgg);
    mfma_gemm_kernel<<<dim3(1, N / 128), 256, 0, stream>>>(
        bufAgg, 96, WT1, b1p, 3, bufH, 96, 96, nullptr, 1);

    // Layer 2
    agg_bf16_v2<96><<<(N * 24 + 255) / 256, 256, 0, stream>>>(bufH, offs, csr_src, csr_w, dinv, bufAgg);
    mfma_gemm_kernel<<<dim3(2, N / 128), 256, 0, stream>>>(
        bufAgg, 96, WT2, b2p, 3, bufH, 160, 160, nullptr, 1);

    // Layer 3
    agg_bf16_v2<160><<<(N * 40 + 255) / 256, 256, 0, stream>>>(bufH, offs, csr_src, csr_w, dinv, bufAgg);
    mfma_gemm_kernel<<<dim3(3, N / 128), 256, 0, stream>>>(
        bufAgg, 160, WT3, b3p, 5, bufH, 320, 320, nullptr, 1);

    // FC + fused scatter; zero only padding rows instead of full 105MB memset
    padzero_kernel<<<dim3(25, N_GRAPHS), 256, 0, stream>>>(startb, out);
    mfma_gemm_kernel<<<dim3(2, N / 128), 256, 0, stream>>>(
        bufH, 320, WTF, bFp, 10, out, 200, 200, rowmap, 0);
}

// Round 4
// 334.581 us; speedup vs baseline: 3.9825x; 1.0192x over previous
//
#include <hip/hip_runtime.h>
#include <hip/hip_bf16.h>
#include <stdint.h>

#define N_NODES 102400
#define N_EDGES 409600
#define N_GRAPHS 2048
#define MAXN 64

typedef __attribute__((ext_vector_type(8))) short short8;
typedef __attribute__((ext_vector_type(4))) float f32x4;

static __device__ __forceinline__ float bfu2f(unsigned short u) {
    union { unsigned int i; float f; } v;
    v.i = ((unsigned int)u) << 16;
    return v.f;
}
static __device__ __forceinline__ unsigned short f2bfu(float f) {
    __hip_bfloat16 h = __float2bfloat16(f);
    return *reinterpret_cast<unsigned short*>(&h);
}

static __device__ __forceinline__ void gload16(const void* g, void* l) {
    __builtin_amdgcn_global_load_lds((const __attribute__((address_space(1))) void*)g,
                                     (__attribute__((address_space(3))) void*)l, 16, 0, 0);
}

// ---------------- degree / CSR build ----------------

__global__ void deg_kernel(const int* __restrict__ dst, int* __restrict__ deg) {
    int e = blockIdx.x * blockDim.x + threadIdx.x;
    if (e < N_EDGES) atomicAdd(&deg[dst[e]], 1);
}

__global__ void dinv_kernel(const int* __restrict__ deg, float* __restrict__ dinv) {
    int i = blockIdx.x * blockDim.x + threadIdx.x;
    if (i < N_NODES) dinv[i] = rsqrtf((float)deg[i] + 1.0f);
}

__global__ void scan1_kernel(const int* __restrict__ deg, int* __restrict__ excl,
                             int* __restrict__ bsum) {
    __shared__ int sh[1024];
    int tid = threadIdx.x;
    int gid = blockIdx.x * 1024 + tid;   // N = 100*1024 exactly
    int v = deg[gid];
    sh[tid] = v;
    __syncthreads();
    for (int off = 1; off < 1024; off <<= 1) {
        int t = (tid >= off) ? sh[tid - off] : 0;
        __syncthreads();
        sh[tid] += t;
        __syncthreads();
    }
    excl[gid] = sh[tid] - v;
    if (tid == 1023) bsum[blockIdx.x] = sh[tid];
}

__global__ void scan2_kernel(int* __restrict__ bsum) {  // 100 entries
    __shared__ int sh[128];
    int tid = threadIdx.x;
    int v = (tid < 100) ? bsum[tid] : 0;
    sh[tid] = v;
    __syncthreads();
    for (int off = 1; off < 128; off <<= 1) {
        int t = (tid >= off) ? sh[tid - off] : 0;
        __syncthreads();
        sh[tid] += t;
        __syncthreads();
    }
    if (tid < 100) bsum[tid] = sh[tid] - v;
}

__global__ void scan3_kernel(const int* __restrict__ excl, const int* __restrict__ bsum,
                             int* __restrict__ offs, int* __restrict__ cursor) {
    int gid = blockIdx.x * blockDim.x + threadIdx.x;
    if (gid < N_NODES) {
        int o = excl[gid] + bsum[gid >> 10];
        offs[gid] = o;
        cursor[gid] = o;
    }
    if (gid == 0) offs[N_NODES] = N_EDGES;
}

__global__ void fill_kernel(const int* __restrict__ src, const int* __restrict__ dst,
                            int* __restrict__ cursor, int* __restrict__ csr_src,
                            float* __restrict__ csr_w, const float* __restrict__ dinv) {
    int e = blockIdx.x * blockDim.x + threadIdx.x;
    if (e >= N_EDGES) return;
    int s = src[e], d = dst[e];
    int pos = atomicAdd(&cursor[d], 1);
    csr_src[pos] = s;
    csr_w[pos] = dinv[s] * dinv[d];
}

// ---------------- to_dense_batch row mapping ----------------

__global__ void start_kernel(const int* __restrict__ batch, int* __restrict__ startb) {
    int i = blockIdx.x * blockDim.x + threadIdx.x;
    if (i >= N_NODES) return;
    if (i == 0 || batch[i] != batch[i - 1]) startb[batch[i]] = i;
    if (i == 0) startb[N_GRAPHS] = N_NODES;
}

__global__ void rowmap_kernel(const int* __restrict__ batch, const int* __restrict__ startb,
                              const int* __restrict__ pmax, int* __restrict__ rowmap) {
    int i = blockIdx.x * blockDim.x + threadIdx.x;
    if (i >= N_NODES) return;
    int b = batch[i];
    int mx = *pmax;
    int pos = i - startb[b];
    rowmap[i] = (pos < mx) ? (b * mx + pos) : -1;
}

// zero only the padding rows of the dense output: rows (b, pos) with pos >= count[b]
__global__ void padzero_kernel(const int* __restrict__ startb, float* __restrict__ out) {
    int b = blockIdx.y;
    int idx = blockIdx.x * blockDim.x + threadIdx.x;  // covers MAXN*100 float2
    int pos = idx / 100;
    int f = idx - pos * 100;
    int count = startb[b + 1] - startb[b];
    if (pos >= count && pos < MAXN) {
        float2 z = {0.0f, 0.0f};
        *(float2*)(out + ((size_t)b * MAXN + pos) * 200 + f * 2) = z;
    }
}

// ---------------- weight prep ----------------

__global__ void prep_w_kernel(const float* __restrict__ W, const float* __restrict__ b,
                              int K, int Nc, int Kp, int Na,
                              __hip_bfloat16* __restrict__ WT, float* __restrict__ bp) {
    int i = blockIdx.x * blockDim.x + threadIdx.x;
    int total = Na * Kp;
    if (i < total) {
        int c = i / Kp, k = i - c * Kp;
        float v = (c < Nc && k < K) ? W[k * Nc + c] : 0.0f;
        WT[i] = __float2bfloat16(v);
    }
    if (i < Na) bp[i] = (i < Nc) ? b[i] : 0.0f;
}

// ---------------- aggregation: thread-per-(node, chunk), 4-way edge unroll ----------

// Layer 1: X fp32 [N,78] -> out bf16 [N,96]. C=48 chunks of 2 cols.
__global__ __launch_bounds__(256) void agg_f32_v2(
    const float* __restrict__ X,
    const int* __restrict__ offs, const int* __restrict__ csr_src,
    const float* __restrict__ csr_w, const float* __restrict__ dinv,
    __hip_bfloat16* __restrict__ out) {
    constexpr int C = 48;
    int idx = blockIdx.x * blockDim.x + threadIdx.x;
    if (idx >= N_NODES * C) return;
    int node = idx / C;
    int c = idx - node * C;
    int col = c * 2;
    float a0 = 0.0f, a1 = 0.0f;
    if (col < 78) {
        float di = dinv[node];
        float sw = di * di;
        const float* Xr = X + (size_t)node * 78 + col;
        float2 h = *(const float2*)Xr;
        a0 = sw * h.x;
        a1 = sw * h.y;
        int e0 = offs[node], e1 = offs[node + 1];
        int j = e0;
        for (; j + 4 <= e1; j += 4) {
            int s0 = csr_src[j], s1 = csr_src[j + 1], s2 = csr_src[j + 2], s3 = csr_src[j + 3];
            float w0 = csr_w[j], w1 = csr_w[j + 1], w2 = csr_w[j + 2], w3 = csr_w[j + 3];
            float2 v0 = *(const float2*)(X + (size_t)s0 * 78 + col);
            float2 v1 = *(const float2*)(X + (size_t)s1 * 78 + col);
            float2 v2 = *(const float2*)(X + (size_t)s2 * 78 + col);
            float2 v3 = *(const float2*)(X + (size_t)s3 * 78 + col);
            a0 += w0 * v0.x + w1 * v1.x + w2 * v2.x + w3 * v3.x;
            a1 += w0 * v0.y + w1 * v1.y + w2 * v2.y + w3 * v3.y;
        }
        for (; j < e1; ++j) {
            int s = csr_src[j];
            float w = csr_w[j];
            float2 v = *(const float2*)(X + (size_t)s * 78 + col);
            a0 += w * v.x;
            a1 += w * v.y;
        }
    }
    __hip_bfloat162 r;
    r.x = __float2bfloat16(a0);
    r.y = __float2bfloat16(a1);
    *(__hip_bfloat162*)(out + (size_t)node * 96 + col) = r;
}

// Layers 2/3: H bf16 [N,LD] -> out bf16 [N,LD]. C=LD/4 chunks of 4 cols.
template <int LD>
__global__ __launch_bounds__(256) void agg_bf16_v2(
    const __hip_bfloat16* __restrict__ H,
    const int* __restrict__ offs, const int* __restrict__ csr_src,
    const float* __restrict__ csr_w, const float* __restrict__ dinv,
    __hip_bfloat16* __restrict__ out) {
    constexpr int C = LD / 4;
    int idx = blockIdx.x * blockDim.x + threadIdx.x;
    if (idx >= N_NODES * C) return;
    int node = idx / C;
    int c = idx - node * C;
    const unsigned short* Hu = (const unsigned short*)H;
    size_t rowoff = (size_t)node * LD + c * 4;
    float di = dinv[node];
    float sw = di * di;
    ushort4 h = *(const ushort4*)(Hu + rowoff);
    float a0 = sw * bfu2f(h.x), a1 = sw * bfu2f(h.y), a2 = sw * bfu2f(h.z), a3 = sw * bfu2f(h.w);
    int e0 = offs[node], e1 = offs[node + 1];
    int j = e0;
    for (; j + 4 <= e1; j += 4) {
        int s0 = csr_src[j], s1 = csr_src[j + 1], s2 = csr_src[j + 2], s3 = csr_src[j + 3];
        float w0 = csr_w[j], w1 = csr_w[j + 1], w2 = csr_w[j + 2], w3 = csr_w[j + 3];
        ushort4 v0 = *(const ushort4*)(Hu + (size_t)s0 * LD + c * 4);
        ushort4 v1 = *(const ushort4*)(Hu + (size_t)s1 * LD + c * 4);
        ushort4 v2 = *(const ushort4*)(Hu + (size_t)s2 * LD + c * 4);
        ushort4 v3 = *(const ushort4*)(Hu + (size_t)s3 * LD + c * 4);
        a0 += w0 * bfu2f(v0.x) + w1 * bfu2f(v1.x) + w2 * bfu2f(v2.x) + w3 * bfu2f(v3.x);
        a1 += w0 * bfu2f(v0.y) + w1 * bfu2f(v1.y) + w2 * bfu2f(v2.y) + w3 * bfu2f(v3.y);
        a2 += w0 * bfu2f(v0.z) + w1 * bfu2f(v1.z) + w2 * bfu2f(v2.z) + w3 * bfu2f(v3.z);
        a3 += w0 * bfu2f(v0.w) + w1 * bfu2f(v1.w) + w2 * bfu2f(v2.w) + w3 * bfu2f(v3.w);
    }
    for (; j < e1; ++j) {
        int s = csr_src[j];
        float w = csr_w[j];
        ushort4 v = *(const ushort4*)(Hu + (size_t)s * LD + c * 4);
        a0 += w * bfu2f(v.x);
        a1 += w * bfu2f(v.y);
        a2 += w * bfu2f(v.z);
        a3 += w * bfu2f(v.w);
    }
    ushort4 r;
    r.x = f2bfu(a0);
    r.y = f2bfu(a1);
    r.z = f2bfu(a2);
    r.w = f2bfu(a3);
    *(ushort4*)((unsigned short*)out + rowoff) = r;
}

// ---------------- bf16 MFMA GEMM v2: global_load_lds, depth-3 pipeline, counted vmcnt ----
// A: bf16 [N, lda] k-major. WT: bf16 [ntiles*128, lda] (row c = output col c), k-major.
// Tile 128x128, BK=32 (64B of k per row per step). 4 waves, each 64x64.
// LDS: 3 buffers x (A 8KB | B 8KB), linear [row][64B] layout (bank-balanced for
// ds_read_b128 of 16 rows x 4 slots). Waves 0-1 stage A halves, waves 2-3 stage B.

__global__ __launch_bounds__(256) void mfma_gemm_kernel(
    const __hip_bfloat16* __restrict__ A, int lda,
    const __hip_bfloat16* __restrict__ WT,
    const float* __restrict__ biasp, int nsteps,
    void* __restrict__ Cout, int ldc, int ccols,
    const int* __restrict__ rowmap, int relu) {
    __shared__ __align__(16) char lds[49152];  // 3 x 16KB

    const int tid = threadIdx.x;
    const int lane = tid & 63;
    const int wid = tid >> 6;
    const int wr = wid >> 1, wc = wid & 1;
    const int r0 = blockIdx.y * 128;
    const int c0 = blockIdx.x * 128;

    // staging: wave w stages 64 rows (w<2: A half w, w>=2: B half w-2), 4 issues of
    // 16 rows each; lane covers row (lane>>2), 16B slot (lane&3). LDS dest is
    // wave-uniform base; HW scatters lane i at base + i*16 == linear row-major.
    const bool isB = (wid >= 2);
    const int half = wid & 1;
    const int srow = half * 64 + (lane >> 2);
    const size_t ldabytes = (size_t)lda * 2;
    const char* gbase = isB ? (const char*)(WT + (size_t)(c0 + srow) * lda)
                            : (const char*)(A + (size_t)(r0 + srow) * lda);
    gbase += (lane & 3) << 4;
    char* lbase = lds + (isB ? 8192 : 0) + half * 4096;

#define STAGE(s, b)                                                            \
    do {                                                                       \
        const char* g_ = gbase + (size_t)(s) * 64;                             \
        char* l_ = lbase + (b) * 16384;                                        \
        gload16(g_, l_);                                                       \
        gload16(g_ + 16 * ldabytes, l_ + 1024);                                \
        gload16(g_ + 32 * ldabytes, l_ + 2048);                                \
        gload16(g_ + 48 * ldabytes, l_ + 3072);                                \
    } while (0)

    // fragment read offsets (linear layout)
    const int frow = lane & 15;
    const int fsl = (lane >> 4) << 4;
    int aoff[4], boff[4];
#pragma unroll
    for (int m = 0; m < 4; ++m) aoff[m] = (wr * 64 + m * 16 + frow) * 64 + fsl;
#pragma unroll
    for (int n = 0; n < 4; ++n) boff[n] = 8192 + (wc * 64 + n * 16 + frow) * 64 + fsl;

    f32x4 acc[4][4];
#pragma unroll
    for (int m = 0; m < 4; ++m)
#pragma unroll
        for (int n = 0; n < 4; ++n) {
            f32x4 z = {0.0f, 0.0f, 0.0f, 0.0f};
            acc[m][n] = z;
        }

#define COMPUTE(b)                                                                        \
    do {                                                                                  \
        const char* cb_ = lds + (b) * 16384;                                              \
        short8 af[4], bfr[4];                                                             \
        _Pragma("unroll") for (int m = 0; m < 4; ++m) af[m] = *(const short8*)(cb_ + aoff[m]); \
        _Pragma("unroll") for (int n = 0; n < 4; ++n) bfr[n] = *(const short8*)(cb_ + boff[n]); \
        _Pragma("unroll") for (int m = 0; m < 4; ++m)                                     \
            _Pragma("unroll") for (int n = 0; n < 4; ++n)                                 \
                acc[m][n] = __builtin_amdgcn_mfma_f32_16x16x32_bf16(af[m], bfr[n], acc[m][n], 0, 0, 0); \
    } while (0)

    // prologue: 2 stages in flight
    STAGE(0, 0);
    STAGE(1, 1);
    int t = 0;
    for (; t < nsteps - 1; ++t) {
        asm volatile("s_waitcnt vmcnt(4)" ::: "memory");  // stage t landed (own 4 oldest)
        __builtin_amdgcn_s_barrier();
        __builtin_amdgcn_sched_barrier(0);
        if (t + 2 < nsteps) STAGE(t + 2, (t + 2) % 3);  // overwrites buf read at t-1: safe post-barrier
        COMPUTE(t % 3);
        __builtin_amdgcn_sched_barrier(0);
    }
    asm volatile("s_waitcnt vmcnt(0)" ::: "memory");
    __builtin_amdgcn_s_barrier();
    __builtin_amdgcn_sched_barrier(0);
    COMPUTE(t % 3);
#undef STAGE
#undef COMPUTE

    // epilogue: C frag layout col=lane&15, row=(lane>>4)*4+j
    const int crow0 = r0 + wr * 64 + ((lane >> 4) << 2);
    const int ccol0 = c0 + wc * 64 + (lane & 15);
#pragma unroll
    for (int n = 0; n < 4; ++n) {
        int col = ccol0 + n * 16;
        if (col >= ccols) continue;
        float bv = biasp[col];
#pragma unroll
        for (int m = 0; m < 4; ++m) {
#pragma unroll
            for (int j = 0; j < 4; ++j) {
                int row = crow0 + m * 16 + j;
                float v = acc[m][n][j] + bv;
                if (relu) v = fmaxf(v, 0.0f);
                if (rowmap) {
                    int drow = rowmap[row];
                    if (drow >= 0) ((float*)Cout)[(size_t)drow * ldc + col] = v;
                } else {
                    ((__hip_bfloat16*)Cout)[(size_t)row * ldc + col] = __float2bfloat16(v);
                }
            }
        }
    }
}

// ---------------- launch ----------------

static inline char* align256(char* p) {
    return (char*)(((uintptr_t)p + 255) & ~(uintptr_t)255);
}

extern "C" void kernel_launch(void* const* d_in, const int* in_sizes, int n_in,
                              void* d_out, int out_size, void* d_ws, size_t ws_size,
                              hipStream_t stream) {
    const int N = N_NODES, E = N_EDGES;
    const float* x = (const float*)d_in[0];
    const int* ei = (const int*)d_in[1];
    const int* src = ei;
    const int* dst = ei + E;
    const int* batch = (const int*)d_in[2];
    const int* pmax = (const int*)d_in[3];
    const float* W1 = (const float*)d_in[4];
    const float* b1 = (const float*)d_in[5];
    const float* W2 = (const float*)d_in[6];
    const float* b2 = (const float*)d_in[7];
    const float* W3 = (const float*)d_in[8];
    const float* b3 = (const float*)d_in[9];
    const float* Wfc = (const float*)d_in[10];
    const float* bfc = (const float*)d_in[11];
    float* out = (float*)d_out;

    char* p = (char*)d_ws;
    float* dinv = (float*)p;          p = align256(p + (size_t)N * 4);
    int* deg = (int*)p;               p = align256(p + (size_t)N * 4);
    int* offs = (int*)p;              p = align256(p + (size_t)(N + 1) * 4);
    int* cursor = (int*)p;            p = align256(p + (size_t)N * 4);
    int* excl = (int*)p;              p = align256(p + (size_t)N * 4);
    int* bsum = (int*)p;              p = align256(p + 128 * 4);
    int* csr_src = (int*)p;           p = align256(p + (size_t)E * 4);
    float* csr_w = (float*)p;         p = align256(p + (size_t)E * 4);
    int* startb = (int*)p;            p = align256(p + (size_t)(N_GRAPHS + 1) * 4);
    int* rowmap = (int*)p;            p = align256(p + (size_t)N * 4);
    __hip_bfloat16* WT1 = (__hip_bfloat16*)p;  p = align256(p + 128 * 96 * 2);
    float* b1p = (float*)p;           p = align256(p + 128 * 4);
    __hip_bfloat16* WT2 = (__hip_bfloat16*)p;  p = align256(p + 256 * 96 * 2);
    float* b2p = (float*)p;           p = align256(p + 256 * 4);
    __hip_bfloat16* WT3 = (__hip_bfloat16*)p;  p = align256(p + 384 * 160 * 2);
    float* b3p = (float*)p;           p = align256(p + 384 * 4);
    __hip_bfloat16* WTF = (__hip_bfloat16*)p;  p = align256(p + 256 * 320 * 2);
    float* bFp = (float*)p;           p = align256(p + 256 * 4);
    __hip_bfloat16* bufAgg = (__hip_bfloat16*)p;  p = align256(p + (size_t)N * 320 * 2);
    __hip_bfloat16* bufH = (__hip_bfloat16*)p;    p = align256(p + (size_t)N * 320 * 2);

    // degree + CSR
    hipMemsetAsync(deg, 0, (size_t)N * 4, stream);
    deg_kernel<<<(E + 255) / 256, 256, 0, stream>>>(dst, deg);
    dinv_kernel<<<(N + 255) / 256, 256, 0, stream>>>(deg, dinv);
    scan1_kernel<<<100, 1024, 0, stream>>>(deg, excl, bsum);
    scan2_kernel<<<1, 128, 0, stream>>>(bsum);
    scan3_kernel<<<(N + 255) / 256, 256, 0, stream>>>(excl, bsum, offs, cursor);
    fill_kernel<<<(E + 255) / 256, 256, 0, stream>>>(src, dst, cursor, csr_src, csr_w, dinv);

    // dense-batch mapping
    start_kernel<<<(N + 255) / 256, 256, 0, stream>>>(batch, startb);
    rowmap_kernel<<<(N + 255) / 256, 256, 0, stream>>>(batch, startb, pmax, rowmap);

    // weight prep
    prep_w_kernel<<<(128 * 96 + 255) / 256, 256, 0, stream>>>(W1, b1, 78, 78, 96, 128, WT1, b1p);
    prep_w_kernel<<<(256 * 96 + 255) / 256, 256, 0, stream>>>(W2, b2, 78, 156, 96, 256, WT2, b2p);
    prep_w_kernel<<<(384 * 160 + 255) / 256, 256, 0, stream>>>(W3, b3, 156, 312, 160, 384, WT3, b3p);
    prep_w_kernel<<<(256 * 320 + 255) / 256, 256, 0, stream>>>(Wfc, bfc, 312, 200, 320, 256, WTF, bFp);

    // Layer 1
    agg_f32_v2<<<(N * 48 + 255) / 256, 256, 0, stream>>>(x, offs, csr_src, csr_w, dinv, bufAgg);
    mfma_gemm_kernel<<<dim3(1, N / 128), 256, 0, stream>>>(
        bufAgg, 96, WT1, b1p, 3, bufH, 96, 96, nullptr, 1);

    // Layer 2
    agg_bf16_v2<96><<<(N * 24 + 255) / 256, 256, 0, stream>>>(bufH, offs, csr_src, csr_w, dinv, bufAgg);
    mfma_gemm_kernel<<<dim3(2, N / 128), 256, 0, stream>>>(
        bufAgg, 96, WT2, b2p, 3, bufH, 160, 160, nullptr, 1);

    // Layer 3
    agg_bf16_v2<160><<<(N * 40 + 255) / 256, 256, 0, stream>>>(bufH, offs, csr_src, csr_w, dinv, bufAgg);
    mfma_gemm_kernel<<<dim3(3, N / 128), 256, 0, stream>>>(
        bufAgg, 160, WT3, b3p, 5, bufH, 320, 320, nullptr, 1);

    // FC + fused scatter; zero only padding rows instead of full 105MB memset
    padzero_kernel<<<dim3(25, N_GRAPHS), 256, 0, stream>>>(startb, out);
    mfma_gemm_kernel<<<dim3(2, N / 128), 256, 0, stream>>>(
        bufH, 320, WTF, bFp, 10, out, 200, 200, rowmap, 0);
}